// Round 6
// baseline (114.109 us; speedup 1.0000x reference)
//
#include <hip/hip_runtime.h>

#define G_ 64
#define N_ 1024
#define DIN 128
#define DH 256
#define DOUT 10

typedef float floatx4 __attribute__((ext_vector_type(4)));
typedef short shortx8 __attribute__((ext_vector_type(8)));

__device__ __forceinline__ ushort f2bf(float f) {
  unsigned u = __builtin_bit_cast(unsigned, f);
  unsigned r = (u + 0x7FFFu + ((u >> 16) & 1u)) >> 16;   // RNE
  return (ushort)r;
}

// packed f32x2 -> bf16x2, RNE. Non-volatile so the scheduler may reorder.
__device__ __forceinline__ unsigned cvtpk(float a, float b) {
  unsigned r;
  asm("v_cvt_pk_bf16_f32 %0, %1, %2" : "=v"(r) : "v"(a), "v"(b));
  return r;
}

// ---------------------------------------------------------------------------
// k1: W1-transpose + per-node norms + per-block u-partials. No xb store:
// k2 re-reads x (L3-hot after this kernel). 1024 blocks x 256 threads;
// block owns 64 nodes; wave does 2 rows/iter via float4 (16B/lane), norm
// reduce = 5 shfl_xor per 2 rows; u kept per-lane, one LDS reduce at end.
// ---------------------------------------------------------------------------
__global__ __launch_bounds__(256) void k1(
    const float* __restrict__ x, const float* __restrict__ W1,
    ushort* __restrict__ w1t, float* __restrict__ u_part,
    float* __restrict__ norminv) {
  const int bid = blockIdx.x;
  const int tid = threadIdx.x;
  const int wave = tid >> 6;
  const int lane = tid & 63;
  const int half = lane >> 5;
  const int l32 = lane & 31;
  const int m0 = bid << 6;

  __shared__ float red[8][DIN];

  // W1 [128][256] f32 -> w1t [256][128] bf16 (blocks 0..127)
  if (bid < DIN)
    w1t[(size_t)tid * DIN + bid] = f2bf(W1[(size_t)bid * DH + tid]);

  float a0 = 0.f, a1 = 0.f, a2 = 0.f, a3 = 0.f;
  #pragma unroll
  for (int it = 0; it < 8; ++it) {
    const int m = m0 + (wave << 4) + (it << 1) + half;
    const float4 v = ((const float4*)(x + (size_t)m * DIN))[l32];
    float ss = v.x * v.x + v.y * v.y + v.z * v.z + v.w * v.w;
    #pragma unroll
    for (int off = 16; off; off >>= 1) ss += __shfl_xor(ss, off, 64);
    const float ninv = rsqrtf(ss + 1e-24f);
    if (l32 == 0) norminv[m] = ninv;
    a0 = fmaf(v.x, ninv, a0);
    a1 = fmaf(v.y, ninv, a1);
    a2 = fmaf(v.z, ninv, a2);
    a3 = fmaf(v.w, ninv, a3);
  }
  float4 av; av.x = a0; av.y = a1; av.z = a2; av.w = a3;
  ((float4*)red[(wave << 1) + half])[l32] = av;
  __syncthreads();
  if (tid < DIN) {
    float s = 0.f;
    #pragma unroll
    for (int i = 0; i < 8; ++i) s += red[i][tid];
    u_part[bid * DIN + tid] = s;
  }
}

// ---------------------------------------------------------------------------
// k2: fused s + MFMA -> per-block hw-partials, reading x in fp32 (L3-hot).
// The s-dot (x[m].u) runs on the MFMA pipe: u is packed as a B-operand
// nonzero only on l16==0 lanes (hi+lo bf16 split for fp32-grade precision),
// so acc_u's C-column 0 holds the dot for rows quad*4+r on lane quad*16;
// one shuffle per r broadcasts it. This removes the 32-deep serial fmaf
// chain that made round-5's k2 latency-bound. 1024 blocks x 256 threads
// (64 nodes/block, mt loop = 4) for higher occupancy; graph g = bid>>4.
// ---------------------------------------------------------------------------
__global__ __launch_bounds__(256) void k2(
    const float* __restrict__ x, const ushort* __restrict__ w1t,
    const float* __restrict__ b1, const float* __restrict__ u_part,
    const float* __restrict__ norminv, float* __restrict__ hw_part) {
  const int bid = blockIdx.x;
  const int tid = threadIdx.x;
  const int wave = tid >> 6;
  const int lane = tid & 63;
  const int g = bid >> 4;
  const int m0 = bid << 6;           // 64 nodes per block
  const int quad = lane >> 4;
  const int l16 = lane & 15;

  __shared__ float u_lds[DIN];
  __shared__ float ninv_lds[64];

  // u for graph g = sum of its 16 block partials; ninv for block's 64 rows
  if (tid < DIN) {
    float s = 0.f;
    #pragma unroll
    for (int i = 0; i < 16; ++i) s += u_part[((g << 4) + i) * DIN + tid];
    u_lds[tid] = s;
  } else if (tid < 192) {
    ninv_lds[tid - 128] = norminv[m0 + tid - 128];
  }
  __syncthreads();

  // u as B-frags (hi+lo bf16 split), nonzero only on l16==0 lanes.
  // B[k][n]: n=l16, k=quad*8+j (+kt*32)  ->  column 0 carries u.
  shortx8 buh[4], bul[4];
  #pragma unroll
  for (int kt = 0; kt < 4; ++kt) {
    shortx8 h, l;
    #pragma unroll
    for (int j = 0; j < 8; ++j) {
      const float uv = (l16 == 0) ? u_lds[(kt << 5) + (quad << 3) + j] : 0.f;
      const ushort uh = f2bf(uv);
      const float uhf = __builtin_bit_cast(float, (unsigned)uh << 16);
      h[j] = (short)uh;
      l[j] = (short)f2bf(uv - uhf);
    }
    buh[kt] = h;
    bul[kt] = l;
  }

  // B fragments: wave's 64-d slice of W1t; B[k][n]: n=l16, k=quad*8+j
  shortx8 bfr[4][4];
  #pragma unroll
  for (int dt = 0; dt < 4; ++dt) {
    const int d = (wave << 6) + (dt << 4) + l16;
    #pragma unroll
    for (int kt = 0; kt < 4; ++kt)
      bfr[dt][kt] =
          *(const shortx8*)(w1t + (size_t)d * DIN + (kt << 5) + (quad << 3));
  }
  float b1v[4];
  #pragma unroll
  for (int dt = 0; dt < 4; ++dt) b1v[dt] = b1[(wave << 6) + (dt << 4) + l16];

  float wsum[4] = {0.f, 0.f, 0.f, 0.f};
  for (int mt = 0; mt < 4; ++mt) {
    // lane's row: m = mt*16 + l16; slices kt*32 + quad*8 .. +8 (2 x float4)
    const float4* xr =
        (const float4*)(x + ((size_t)m0 + (mt << 4) + l16) * DIN);
    shortx8 af[4];
    #pragma unroll
    for (int kt = 0; kt < 4; ++kt) {
      const float4 fa = xr[(kt << 3) + (quad << 1)];
      const float4 fb = xr[(kt << 3) + (quad << 1) + 1];
      uint4 pk;
      pk.x = cvtpk(fa.x, fa.y);
      pk.y = cvtpk(fa.z, fa.w);
      pk.z = cvtpk(fb.x, fb.y);
      pk.w = cvtpk(fb.z, fb.w);
      af[kt] = __builtin_bit_cast(shortx8, pk);
    }

    floatx4 acc[4] = {{0.f, 0.f, 0.f, 0.f}, {0.f, 0.f, 0.f, 0.f},
                      {0.f, 0.f, 0.f, 0.f}, {0.f, 0.f, 0.f, 0.f}};
    floatx4 accu = {0.f, 0.f, 0.f, 0.f};
    #pragma unroll
    for (int kt = 0; kt < 4; ++kt) {
      #pragma unroll
      for (int dt = 0; dt < 4; ++dt)
        acc[dt] = __builtin_amdgcn_mfma_f32_16x16x32_bf16(af[kt], bfr[dt][kt],
                                                          acc[dt], 0, 0, 0);
      accu = __builtin_amdgcn_mfma_f32_16x16x32_bf16(af[kt], buh[kt], accu,
                                                     0, 0, 0);
      accu = __builtin_amdgcn_mfma_f32_16x16x32_bf16(af[kt], bul[kt], accu,
                                                     0, 0, 0);
    }

    // s for tile-rows quad*4+r: C col 0 lives on lane quad*16, reg r
    float sv[4];
    #pragma unroll
    for (int r = 0; r < 4; ++r) {
      const float dot = __shfl(accu[r], lane & 48, 64);
      sv[r] = dot * ninv_lds[(mt << 4) + (quad << 2) + r] - 1.0f;
    }

    #pragma unroll
    for (int dt = 0; dt < 4; ++dt) {
      float bs = 0.f;
      #pragma unroll
      for (int r = 0; r < 4; ++r) {
        const float h = fmaxf(acc[dt][r] + b1v[dt], 0.f);
        bs = fmaf(sv[r], h, bs);
      }
      wsum[dt] += bs;
    }
  }
  #pragma unroll
  for (int dt = 0; dt < 4; ++dt) {
    float w = wsum[dt];
    w += __shfl_xor(w, 16, 64);
    w += __shfl_xor(w, 32, 64);
    if (quad == 0)
      hw_part[bid * DH + (wave << 6) + (dt << 4) + l16] = w;
  }
}

// ---------------------------------------------------------------------------
// k3: head. One 256-thread block per graph: sum 16 hw_part slices, fc2,
// mean-pool, log-softmax.
// ---------------------------------------------------------------------------
__global__ __launch_bounds__(256) void k3(
    const float* __restrict__ hw_part, const float* __restrict__ W2,
    const float* __restrict__ b2, float* __restrict__ out) {
  const int g = blockIdx.x;
  const int tid = threadIdx.x;
  __shared__ float hv[DH];
  __shared__ float partial[40];
  __shared__ float pv[DOUT];

  float h = 0.f;
  #pragma unroll
  for (int i = 0; i < 16; ++i) h += hw_part[((g << 4) + i) * DH + tid];
  hv[tid] = h;
  __syncthreads();
  if (tid < 40) {
    const int c = tid % 10, q = tid / 10;
    float a = 0.f;
    #pragma unroll
    for (int k = 0; k < 64; ++k)
      a = fmaf(hv[q * 64 + k], W2[(q * 64 + k) * DOUT + c], a);
    partial[tid] = a;
  }
  __syncthreads();
  if (tid < DOUT) {
    pv[tid] = (partial[tid] + partial[tid + 10] + partial[tid + 20] +
               partial[tid + 30]) * (1.0f / N_) + b2[tid];
  }
  __syncthreads();
  if (tid < DOUT) {
    float mx = pv[0];
    #pragma unroll
    for (int c = 1; c < DOUT; ++c) mx = fmaxf(mx, pv[c]);
    float se = 0.f;
    #pragma unroll
    for (int c = 0; c < DOUT; ++c) se += expf(pv[c] - mx);
    out[g * DOUT + tid] = pv[tid] - (mx + logf(se));
  }
}

extern "C" void kernel_launch(void* const* d_in, const int* in_sizes, int n_in,
                              void* d_out, int out_size, void* d_ws, size_t ws_size,
                              hipStream_t stream) {
  const float* x  = (const float*)d_in[0];
  // d_in[1] = batch (sorted, equal-sized) -> unused
  const float* W1 = (const float*)d_in[2];
  const float* b1 = (const float*)d_in[3];
  const float* W2 = (const float*)d_in[4];
  const float* b2 = (const float*)d_in[5];
  float* out = (float*)d_out;

  // ws layout: w1t [256][128] bf16 (64 KB) | u_part [1024][128] f32 (512 KB)
  //   | hw_part [1024][256] f32 (1 MB) | norminv [65536] f32 (256 KB)
  ushort* w1t = (ushort*)d_ws;
  float* u_part  = (float*)(w1t + (size_t)DH * DIN);
  float* hw_part = u_part + (size_t)1024 * DIN;
  float* norminv = hw_part + (size_t)1024 * DH;

  k1<<<1024, 256, 0, stream>>>(x, W1, w1t, u_part, norminv);
  k2<<<1024, 256, 0, stream>>>(x, w1t, b1, u_part, norminv, hw_part);
  k3<<<G_, 256, 0, stream>>>(hw_part, W2, b2, out);
}

// Round 7
// 106.373 us; speedup vs baseline: 1.0727x; 1.0727x over previous
//
#include <hip/hip_runtime.h>

#define G_ 64
#define N_ 1024
#define DIN 128
#define DH 256
#define DOUT 10

typedef float floatx4 __attribute__((ext_vector_type(4)));
typedef short shortx8 __attribute__((ext_vector_type(8)));

__device__ __forceinline__ ushort f2bf(float f) {
  unsigned u = __builtin_bit_cast(unsigned, f);
  unsigned r = (u + 0x7FFFu + ((u >> 16) & 1u)) >> 16;   // RNE
  return (ushort)r;
}

// packed f32x2 -> bf16x2, RNE. Non-volatile so the scheduler may reorder.
__device__ __forceinline__ unsigned cvtpk(float a, float b) {
  unsigned r;
  asm("v_cvt_pk_bf16_f32 %0, %1, %2" : "=v"(r) : "v"(a), "v"(b));
  return r;
}
__device__ __forceinline__ float bflo(unsigned q) {
  return __builtin_bit_cast(float, q << 16);
}
__device__ __forceinline__ float bfhi(unsigned q) {
  return __builtin_bit_cast(float, q & 0xFFFF0000u);
}

// ---------------------------------------------------------------------------
// k1: W1-transpose + per-node norms + per-block u-partials. No xb store:
// k2 re-reads x (L3-hot after this kernel). 1024 blocks x 256 threads;
// block owns 64 nodes; wave does 2 rows/iter via float4 (16B/lane), norm
// reduce = 5 shfl_xor per 2 rows; u kept per-lane, one LDS reduce at end.
// ---------------------------------------------------------------------------
__global__ __launch_bounds__(256) void k1(
    const float* __restrict__ x, const float* __restrict__ W1,
    ushort* __restrict__ w1t, float* __restrict__ u_part,
    float* __restrict__ norminv) {
  const int bid = blockIdx.x;
  const int tid = threadIdx.x;
  const int wave = tid >> 6;
  const int lane = tid & 63;
  const int half = lane >> 5;
  const int l32 = lane & 31;
  const int m0 = bid << 6;

  __shared__ float red[8][DIN];

  // W1 [128][256] f32 -> w1t [256][128] bf16 (blocks 0..127)
  if (bid < DIN)
    w1t[(size_t)tid * DIN + bid] = f2bf(W1[(size_t)bid * DH + tid]);

  float a0 = 0.f, a1 = 0.f, a2 = 0.f, a3 = 0.f;
  #pragma unroll
  for (int it = 0; it < 8; ++it) {
    const int m = m0 + (wave << 4) + (it << 1) + half;
    const float4 v = ((const float4*)(x + (size_t)m * DIN))[l32];
    float ss = v.x * v.x + v.y * v.y + v.z * v.z + v.w * v.w;
    #pragma unroll
    for (int off = 16; off; off >>= 1) ss += __shfl_xor(ss, off, 64);
    const float ninv = rsqrtf(ss + 1e-24f);
    if (l32 == 0) norminv[m] = ninv;
    a0 = fmaf(v.x, ninv, a0);
    a1 = fmaf(v.y, ninv, a1);
    a2 = fmaf(v.z, ninv, a2);
    a3 = fmaf(v.w, ninv, a3);
  }
  float4 av; av.x = a0; av.y = a1; av.z = a2; av.w = a3;
  ((float4*)red[(wave << 1) + half])[l32] = av;
  __syncthreads();
  if (tid < DIN) {
    float s = 0.f;
    #pragma unroll
    for (int i = 0; i < 8; ++i) s += red[i][tid];
    u_part[bid * DIN + tid] = s;
  }
}

// ---------------------------------------------------------------------------
// k2: fused s + MFMA -> per-block hw-partials, reading x in fp32 (L3-hot).
// The s-dot (x[m].u) runs on the otherwise-idle MFMA pipe: u packed as a
// B-operand nonzero only on l16==0 lanes (hi+lo bf16 split keeps fp32-grade
// dot precision; verified round 6). accu C-column 0 then holds the dot for
// rows quad*4+r on lane quad*16; one shuffle per r broadcasts it. The u-frag
// build uses cvt_pk + bit-ops (~100 VALU total, vs round-6's ~640) and is
// amortized over mt=8 (128 nodes/block, 512 blocks). Round-6's regression
// was prologue cost x block count, not the MFMA-dot idea.
// ---------------------------------------------------------------------------
__global__ __launch_bounds__(256) void k2(
    const float* __restrict__ x, const ushort* __restrict__ w1t,
    const float* __restrict__ b1, const float* __restrict__ u_part,
    const float* __restrict__ norminv, float* __restrict__ hw_part) {
  const int bid = blockIdx.x;
  const int tid = threadIdx.x;
  const int wave = tid >> 6;
  const int lane = tid & 63;
  const int g = bid >> 3;
  const int m0 = bid << 7;           // 128 nodes per block
  const int quad = lane >> 4;
  const int l16 = lane & 15;

  __shared__ float u_lds[DIN];
  __shared__ float ninv_lds[128];

  // u for graph g = sum of its 16 k1-block partials; ninv for 128 rows
  if (tid < DIN) {
    float s = 0.f;
    #pragma unroll
    for (int i = 0; i < 16; ++i) s += u_part[((g << 4) + i) * DIN + tid];
    u_lds[tid] = s;
  } else {
    ninv_lds[tid - 128] = norminv[m0 + tid - 128];
  }
  __syncthreads();

  // u as B-frags (hi+lo bf16 split), nonzero only on l16==0 lanes.
  // B[k][n]: n=l16, k=quad*8+j (+kt*32) -> column 0 carries u.
  shortx8 buh[4], bul[4];
  #pragma unroll
  for (int kt = 0; kt < 4; ++kt) {
    const float* ub = &u_lds[(kt << 5) + (quad << 3)];
    uint4 h4, l4;
    #pragma unroll
    for (int pr = 0; pr < 4; ++pr) {
      const float ua = ub[2 * pr], ubv = ub[2 * pr + 1];
      const unsigned w = cvtpk(ua, ubv);
      ((unsigned*)&h4)[pr] = w;
      ((unsigned*)&l4)[pr] = cvtpk(ua - bflo(w), ubv - bfhi(w));
    }
    const uint4 z = {0u, 0u, 0u, 0u};
    buh[kt] = __builtin_bit_cast(shortx8, (l16 == 0) ? h4 : z);
    bul[kt] = __builtin_bit_cast(shortx8, (l16 == 0) ? l4 : z);
  }

  // B fragments: wave's 64-d slice of W1t; B[k][n]: n=l16, k=quad*8+j
  shortx8 bfr[4][4];
  #pragma unroll
  for (int dt = 0; dt < 4; ++dt) {
    const int d = (wave << 6) + (dt << 4) + l16;
    #pragma unroll
    for (int kt = 0; kt < 4; ++kt)
      bfr[dt][kt] =
          *(const shortx8*)(w1t + (size_t)d * DIN + (kt << 5) + (quad << 3));
  }
  float b1v[4];
  #pragma unroll
  for (int dt = 0; dt < 4; ++dt) b1v[dt] = b1[(wave << 6) + (dt << 4) + l16];

  float wsum[4] = {0.f, 0.f, 0.f, 0.f};
  for (int mt = 0; mt < 8; ++mt) {
    // lane's row: m = mt*16 + l16; slices kt*32 + quad*8 .. +8 (2 x float4)
    const float4* xr =
        (const float4*)(x + ((size_t)m0 + (mt << 4) + l16) * DIN);
    shortx8 af[4];
    #pragma unroll
    for (int kt = 0; kt < 4; ++kt) {
      const float4 fa = xr[(kt << 3) + (quad << 1)];
      const float4 fb = xr[(kt << 3) + (quad << 1) + 1];
      uint4 pk;
      pk.x = cvtpk(fa.x, fa.y);
      pk.y = cvtpk(fa.z, fa.w);
      pk.z = cvtpk(fb.x, fb.y);
      pk.w = cvtpk(fb.z, fb.w);
      af[kt] = __builtin_bit_cast(shortx8, pk);
    }

    floatx4 acc[4] = {{0.f, 0.f, 0.f, 0.f}, {0.f, 0.f, 0.f, 0.f},
                      {0.f, 0.f, 0.f, 0.f}, {0.f, 0.f, 0.f, 0.f}};
    floatx4 accu = {0.f, 0.f, 0.f, 0.f};
    #pragma unroll
    for (int kt = 0; kt < 4; ++kt) {
      #pragma unroll
      for (int dt = 0; dt < 4; ++dt)
        acc[dt] = __builtin_amdgcn_mfma_f32_16x16x32_bf16(af[kt], bfr[dt][kt],
                                                          acc[dt], 0, 0, 0);
      accu = __builtin_amdgcn_mfma_f32_16x16x32_bf16(af[kt], buh[kt], accu,
                                                     0, 0, 0);
      accu = __builtin_amdgcn_mfma_f32_16x16x32_bf16(af[kt], bul[kt], accu,
                                                     0, 0, 0);
    }

    // s for tile-rows quad*4+r: C col 0 lives on lane quad*16, reg r
    float sv[4];
    #pragma unroll
    for (int r = 0; r < 4; ++r) {
      const float dot = __shfl(accu[r], lane & 48, 64);
      sv[r] = dot * ninv_lds[(mt << 4) + (quad << 2) + r] - 1.0f;
    }

    #pragma unroll
    for (int dt = 0; dt < 4; ++dt) {
      float bs = 0.f;
      #pragma unroll
      for (int r = 0; r < 4; ++r) {
        const float h = fmaxf(acc[dt][r] + b1v[dt], 0.f);
        bs = fmaf(sv[r], h, bs);
      }
      wsum[dt] += bs;
    }
  }
  #pragma unroll
  for (int dt = 0; dt < 4; ++dt) {
    float w = wsum[dt];
    w += __shfl_xor(w, 16, 64);
    w += __shfl_xor(w, 32, 64);
    if (quad == 0)
      hw_part[bid * DH + (wave << 6) + (dt << 4) + l16] = w;
  }
}

// ---------------------------------------------------------------------------
// k3: head. One 256-thread block per graph: sum 8 hw_part slices, fc2,
// mean-pool, log-softmax.
// ---------------------------------------------------------------------------
__global__ __launch_bounds__(256) void k3(
    const float* __restrict__ hw_part, const float* __restrict__ W2,
    const float* __restrict__ b2, float* __restrict__ out) {
  const int g = blockIdx.x;
  const int tid = threadIdx.x;
  __shared__ float hv[DH];
  __shared__ float partial[40];
  __shared__ float pv[DOUT];

  float h = 0.f;
  #pragma unroll
  for (int i = 0; i < 8; ++i) h += hw_part[((g << 3) + i) * DH + tid];
  hv[tid] = h;
  __syncthreads();
  if (tid < 40) {
    const int c = tid % 10, q = tid / 10;
    float a = 0.f;
    #pragma unroll
    for (int k = 0; k < 64; ++k)
      a = fmaf(hv[q * 64 + k], W2[(q * 64 + k) * DOUT + c], a);
    partial[tid] = a;
  }
  __syncthreads();
  if (tid < DOUT) {
    pv[tid] = (partial[tid] + partial[tid + 10] + partial[tid + 20] +
               partial[tid + 30]) * (1.0f / N_) + b2[tid];
  }
  __syncthreads();
  if (tid < DOUT) {
    float mx = pv[0];
    #pragma unroll
    for (int c = 1; c < DOUT; ++c) mx = fmaxf(mx, pv[c]);
    float se = 0.f;
    #pragma unroll
    for (int c = 0; c < DOUT; ++c) se += expf(pv[c] - mx);
    out[g * DOUT + tid] = pv[tid] - (mx + logf(se));
  }
}

extern "C" void kernel_launch(void* const* d_in, const int* in_sizes, int n_in,
                              void* d_out, int out_size, void* d_ws, size_t ws_size,
                              hipStream_t stream) {
  const float* x  = (const float*)d_in[0];
  // d_in[1] = batch (sorted, equal-sized) -> unused
  const float* W1 = (const float*)d_in[2];
  const float* b1 = (const float*)d_in[3];
  const float* W2 = (const float*)d_in[4];
  const float* b2 = (const float*)d_in[5];
  float* out = (float*)d_out;

  // ws layout: w1t [256][128] bf16 (64 KB) | u_part [1024][128] f32 (512 KB)
  //   | hw_part [512][256] f32 (512 KB) | norminv [65536] f32 (256 KB)
  ushort* w1t = (ushort*)d_ws;
  float* u_part  = (float*)(w1t + (size_t)DH * DIN);
  float* hw_part = u_part + (size_t)1024 * DIN;
  float* norminv = hw_part + (size_t)512 * DH;

  k1<<<1024, 256, 0, stream>>>(x, W1, w1t, u_part, norminv);
  k2<<<512, 256, 0, stream>>>(x, w1t, b1, u_part, norminv, hw_part);
  k3<<<G_, 256, 0, stream>>>(hw_part, W2, b2, out);
}